// Round 1
// baseline (1923.708 us; speedup 1.0000x reference)
//
#include <hip/hip_runtime.h>

#define NN 50000      // nodes
#define NE 800000     // edges
#define F  64         // feature dim
#define ATN 65        // NsT stride: 65 % 32 == 1 -> transposed agg stores spread all 32 banks (2-way, free)
#define SCAN_B 49     // scan blocks: 49 * 1024 >= 50000

typedef float f32x4 __attribute__((ext_vector_type(4)));

// bf16 round-to-nearest-even, returns low-16 bits
__device__ __forceinline__ unsigned bf16rne(float f) {
    unsigned u = __float_as_uint(f);
    return (u + 0x7fffu + ((u >> 16) & 1u)) >> 16;
}
__device__ __forceinline__ float bflo(unsigned p) { return __uint_as_float(p << 16); }
__device__ __forceinline__ float bfhi(unsigned p) { return __uint_as_float(p & 0xffff0000u); }

// ---------------- fused: edge degree count+slot  AND  embedding gather ----------------

__launch_bounds__(256)
__global__ void k_count_gather(const int* __restrict__ dst, int* __restrict__ cnt,
                               unsigned short* __restrict__ pos,
                               const float* __restrict__ embed, const int* __restrict__ ids,
                               uint2* __restrict__ xb) {
    int t = blockIdx.x * blockDim.x + threadIdx.x;
    if (t < NE) pos[t] = (unsigned short)atomicAdd(&cnt[dst[t]], 1);
    if (t < NN * 16) {
        int i = t >> 4, c = t & 15;
        float4 v = ((const float4*)embed)[ids[i] * 16 + c];
        uint2 p;
        p.x = bf16rne(v.x) | (bf16rne(v.y) << 16);
        p.y = bf16rne(v.z) | (bf16rne(v.w) << 16);
        xb[t] = p;
    }
}

// ---- 2-dispatch scan: block partials, then per-block redundant scan of partials ----

__launch_bounds__(256)
__global__ void k_scan_a(const int* __restrict__ cnt, int* __restrict__ partials) {
    __shared__ int sc[256];
    int t = threadIdx.x;
    int base = blockIdx.x * 1024 + t * 4;
    int s = 0;
#pragma unroll
    for (int k = 0; k < 4; ++k) {
        int idx = base + k;
        s += (idx < NN) ? cnt[idx] : 0;
    }
    sc[t] = s;
    __syncthreads();
    for (int d = 128; d > 0; d >>= 1) {
        if (t < d) sc[t] += sc[t + d];
        __syncthreads();
    }
    if (t == 0) partials[blockIdx.x] = sc[0];
}

__launch_bounds__(256)
__global__ void k_scan_c2(const int* __restrict__ cnt, const int* __restrict__ partials,
                          int* __restrict__ offs) {
    __shared__ int sboff;
    __shared__ int stotal;
    __shared__ int sc[256];
    int t = threadIdx.x;
    if (t < 64) {  // wave 0 redundantly scans the 49 partials
        int v = (t < SCAN_B) ? partials[t] : 0;
        int orig = v;
        for (int d = 1; d < 64; d <<= 1) {
            int u = __shfl_up(v, d);
            if (t >= d) v += u;
        }
        if (t == (int)blockIdx.x) sboff = v - orig;
        if (t == 63) stotal = v;
    }
    int base = blockIdx.x * 1024 + t * 4;
    int v4[4];
#pragma unroll
    for (int k = 0; k < 4; ++k) {
        int idx = base + k;
        v4[k] = (idx < NN) ? cnt[idx] : 0;
    }
    int lsum = v4[0] + v4[1] + v4[2] + v4[3];
    sc[t] = lsum;
    __syncthreads();
    for (int d = 1; d < 256; d <<= 1) {
        int u = (t >= d) ? sc[t - d] : 0;
        __syncthreads();
        sc[t] += u;
        __syncthreads();
    }
    int run = sboff + sc[t] - lsum;
#pragma unroll
    for (int k = 0; k < 4; ++k) {
        int idx = base + k;
        if (idx < NN) { offs[idx] = run; run += v4[k]; }
    }
    if (blockIdx.x == 0 && t == 0) offs[NN] = stotal;
}

// atomic-free fill: slot was precomputed in pos[]
__global__ void k_fill(const int* __restrict__ src, const int* __restrict__ dst,
                       const int* __restrict__ offs, const unsigned short* __restrict__ pos,
                       int* __restrict__ csr) {
    int e = blockIdx.x * blockDim.x + threadIdx.x;
    if (e < NE) csr[offs[dst[e]] + (int)pos[e]] = src[e];
}

// ---------------- fused layer: aggregate + GEMM in one kernel ----------------
// 512 threads, 64 nodes/block. Agg phase: thread = (node, uint4 chunk), 8 lanes
// per node, unroll-8 full-row (128 B) gathers with shfl-broadcast indices;
// result -> NsT (fp32). R11 change: AsT removed from LDS — the GEMM phase
// streams the 64 self rows straight from the bf16 global table (8 KB/block,
// L2-hot, ~+6% of gather traffic) with a 2-deep register pipeline. LDS is now
// NsT (stride 65, conflict-free transposed stores) + Wpk = 33.0 KB -> 4
// blocks/CU (was 3 at 51.2 KB). __launch_bounds__(512,8) pins VGPR <= 64 so
// the 4th block actually fits.
// LAST=false: relu -> bf16 out. LAST=true: second GEMM with Wfc/bfc -> fp32 out
// (h2 tile reuses NsT, Wfc reuses Wpk storage).

__device__ __forceinline__ void add8(float s[8], const uint4 v) {
    s[0] += bflo(v.x); s[1] += bfhi(v.x);
    s[2] += bflo(v.y); s[3] += bfhi(v.y);
    s[4] += bflo(v.z); s[5] += bfhi(v.z);
    s[6] += bflo(v.w); s[7] += bfhi(v.w);
}

template <bool LAST>
__launch_bounds__(512, 8)
__global__ void k_fused(const uint4* __restrict__ Ab, const int* __restrict__ offs,
                        const int* __restrict__ csr,
                        const float* __restrict__ Ws, const float* __restrict__ Wn,
                        const float* __restrict__ b,
                        const float* __restrict__ Wfc, const float* __restrict__ bfc,
                        uint2* __restrict__ outb, float* __restrict__ out) {
    __shared__ alignas(16) float NsT[F * ATN];     // neighbor-mean tile, transposed [f][node]
    __shared__ alignas(16) unsigned Wpk[F * F];    // Ws|Wn<<16 bf16-packed [k][f]

    const int tid = threadIdx.x;
    const int node0 = blockIdx.x * 64;

    // stage packed weights
    for (int i = tid; i < F * F; i += 512)
        Wpk[i] = bf16rne(Ws[i]) | (bf16rne(Wn[i]) << 16);

    // agg: one (node, chunk) item per thread
    {
        const int n = tid >> 3;          // node within tile
        const int c = tid & 7;           // uint4 chunk (8 bf16 feats)
        const int lane = tid & 63;
        const int base = lane & 56;
        const int gnode = node0 + n;
        float s[8] = {0.f, 0.f, 0.f, 0.f, 0.f, 0.f, 0.f, 0.f};
        float inv = 0.f;
        if (gnode < NN) {
            int beg = offs[gnode], end = offs[gnode + 1];
            int j = beg;
            for (; j + 8 <= end; j += 8) {
                int v = csr[j + c];
                int i0 = __shfl(v, base + 0, 64), i1 = __shfl(v, base + 1, 64);
                int i2 = __shfl(v, base + 2, 64), i3 = __shfl(v, base + 3, 64);
                int i4 = __shfl(v, base + 4, 64), i5 = __shfl(v, base + 5, 64);
                int i6 = __shfl(v, base + 6, 64), i7 = __shfl(v, base + 7, 64);
                uint4 d0 = Ab[i0 * 8 + c], d1 = Ab[i1 * 8 + c];
                uint4 d2 = Ab[i2 * 8 + c], d3 = Ab[i3 * 8 + c];
                uint4 d4 = Ab[i4 * 8 + c], d5 = Ab[i5 * 8 + c];
                uint4 d6 = Ab[i6 * 8 + c], d7 = Ab[i7 * 8 + c];
                add8(s, d0); add8(s, d1); add8(s, d2); add8(s, d3);
                add8(s, d4); add8(s, d5); add8(s, d6); add8(s, d7);
            }
            int rem = end - j;
            if (rem > 0) {
                int v = csr[j + (c < rem ? c : 0)];
                int idx[8];
#pragma unroll
                for (int k = 0; k < 8; ++k) idx[k] = __shfl(v, base + k, 64);
#pragma unroll
                for (int k = 0; k < 8; ++k)
                    if (k < rem) { uint4 d = Ab[idx[k] * 8 + c]; add8(s, d); }
            }
            int deg = end - beg;
            inv = (deg > 0) ? 1.f / (float)deg : 0.f;
        }
        const int f = 8 * c;
#pragma unroll
        for (int q = 0; q < 8; ++q) NsT[(f + q) * ATN + n] = s[q] * inv;
    }
    __syncthreads();

    // GEMM: 512 threads = 16(feat-grp) x 32(node-grp); microtile 2 nodes x 4 feats
    // self operand streamed from global Ab (rows are L2/LLC-hot), 2-deep pipeline
    const int tx = tid & 15, ty = tid >> 4;
    const int rbase = (node0 + 2 * ty) * 8;   // uint4 index of this thread's first row
    float acc[2][4];
#pragma unroll
    for (int j = 0; j < 4; ++j) {
        float bv = b[4 * tx + j];
        acc[0][j] = bv; acc[1][j] = bv;
    }
    uint4 a0 = Ab[rbase];
    uint4 a1 = Ab[rbase + 8];
#pragma unroll
    for (int k8 = 0; k8 < 8; ++k8) {
        const uint4 p0 = a0, p1 = a1;
        if (k8 < 7) { a0 = Ab[rbase + k8 + 1]; a1 = Ab[rbase + 8 + k8 + 1]; }
        const float af0[8] = {bflo(p0.x), bfhi(p0.x), bflo(p0.y), bfhi(p0.y),
                              bflo(p0.z), bfhi(p0.z), bflo(p0.w), bfhi(p0.w)};
        const float af1[8] = {bflo(p1.x), bfhi(p1.x), bflo(p1.y), bfhi(p1.y),
                              bflo(p1.z), bfhi(p1.z), bflo(p1.w), bfhi(p1.w)};
#pragma unroll
        for (int kk = 0; kk < 8; ++kk) {
            const int k = 8 * k8 + kk;
            float nx = NsT[k * ATN + 2 * ty];
            float ny = NsT[k * ATN + 2 * ty + 1];
            uint4 wq = *(const uint4*)&Wpk[k * 64 + 4 * tx];
            float ws_[4] = {bflo(wq.x), bflo(wq.y), bflo(wq.z), bflo(wq.w)};
            float wn_[4] = {bfhi(wq.x), bfhi(wq.y), bfhi(wq.z), bfhi(wq.w)};
#pragma unroll
            for (int j = 0; j < 4; ++j) {
                acc[0][j] += af0[kk] * ws_[j] + nx * wn_[j];
                acc[1][j] += af1[kk] * ws_[j] + ny * wn_[j];
            }
        }
    }

    if (!LAST) {
#pragma unroll
        for (int i = 0; i < 2; ++i) {
            int node = node0 + 2 * ty + i;
            if (node < NN) {
                float o0 = acc[i][0] > 0.f ? acc[i][0] : 0.f;
                float o1 = acc[i][1] > 0.f ? acc[i][1] : 0.f;
                float o2 = acc[i][2] > 0.f ? acc[i][2] : 0.f;
                float o3 = acc[i][3] > 0.f ? acc[i][3] : 0.f;
                uint2 p;
                p.x = bf16rne(o0) | (bf16rne(o1) << 16);
                p.y = bf16rne(o2) | (bf16rne(o3) << 16);
                outb[node * 16 + tx] = p;
            }
        }
    } else {
        // fused final GEMM: h2 tile -> NsT (reused); Wfc (fp32) reuses Wpk storage
        __syncthreads();
        float* Wf = (float*)Wpk;
#pragma unroll
        for (int i = 0; i < 2; ++i)
#pragma unroll
            for (int j = 0; j < 4; ++j)
                NsT[(4 * tx + j) * ATN + (2 * ty + i)] = acc[i][j];
        for (int i = tid; i < F * F / 4; i += 512)
            ((float4*)Wf)[i] = ((const float4*)Wfc)[i];
        __syncthreads();

        float acc2[2][4];
#pragma unroll
        for (int j = 0; j < 4; ++j) {
            float bv = bfc[4 * tx + j];
            acc2[0][j] = bv; acc2[1][j] = bv;
        }
#pragma unroll 4
        for (int k = 0; k < 64; ++k) {
            float ax = NsT[k * ATN + 2 * ty];
            float ay = NsT[k * ATN + 2 * ty + 1];
            float4 w4 = *(const float4*)&Wf[k * 64 + 4 * tx];
            float w_[4] = {w4.x, w4.y, w4.z, w4.w};
#pragma unroll
            for (int j = 0; j < 4; ++j) {
                acc2[0][j] += ax * w_[j];
                acc2[1][j] += ay * w_[j];
            }
        }
#pragma unroll
        for (int i = 0; i < 2; ++i) {
            int node = node0 + 2 * ty + i;
            if (node < NN) {
                f32x4 o;
                o.x = acc2[i][0]; o.y = acc2[i][1]; o.z = acc2[i][2]; o.w = acc2[i][3];
                __builtin_nontemporal_store(o, (f32x4*)&out[node * 64 + 4 * tx]);
            }
        }
    }
}

// ---------------- launch ----------------

extern "C" void kernel_launch(void* const* d_in, const int* in_sizes, int n_in,
                              void* d_out, int out_size, void* d_ws, size_t ws_size,
                              hipStream_t stream) {
    const float* embed = (const float*)d_in[0];
    const float* W1s = (const float*)d_in[1];
    const float* W1n = (const float*)d_in[2];
    const float* b1  = (const float*)d_in[3];
    const float* W2s = (const float*)d_in[4];
    const float* W2n = (const float*)d_in[5];
    const float* b2  = (const float*)d_in[6];
    const float* Wfc = (const float*)d_in[7];
    const float* bfc = (const float*)d_in[8];
    const int* ids = (const int*)d_in[9];
    const int* src = (const int*)d_in[10];
    const int* dst = (const int*)d_in[11];
    float* out = (float*)d_out;

    char* ws = (char*)d_ws;
    size_t off = 0;
    auto alloc = [&](size_t nb) {
        char* p = ws + off;
        off = (off + nb + 255) & ~(size_t)255;
        return p;
    };
    int*   cnt      = (int*)alloc(NN * sizeof(int));        // zeroed
    size_t zero_bytes = off;
    int*   offs     = (int*)alloc((NN + 1) * sizeof(int));
    int*   partials = (int*)alloc(SCAN_B * sizeof(int));
    unsigned short* pos = (unsigned short*)alloc(NE * sizeof(unsigned short));
    int*   csr      = (int*)alloc(NE * sizeof(int));
    // +64 rows pad: GEMM self-row streaming reads up to node 50047 (benign garbage, stores guarded)
    uint2* xb       = (uint2*)alloc((size_t)(NN + 64) * 16 * sizeof(uint2));  // bf16 x
    uint2* h1b      = (uint2*)alloc((size_t)(NN + 64) * 16 * sizeof(uint2));  // bf16 h1

    hipMemsetAsync(d_ws, 0, zero_bytes, stream);

    const int TB = 256;
    const int EB = (NE + TB - 1) / TB;     // 3125
    k_count_gather<<<EB, TB, 0, stream>>>(dst, cnt, pos, embed, ids, xb);
    k_scan_a<<<SCAN_B, 256, 0, stream>>>(cnt, partials);
    k_scan_c2<<<SCAN_B, 256, 0, stream>>>(cnt, partials, offs);
    k_fill<<<EB, TB, 0, stream>>>(src, dst, offs, pos, csr);

    const int NB = (NN + 63) / 64;         // 782
    k_fused<false><<<NB, 512, 0, stream>>>((const uint4*)xb, offs, csr,
                                           W1s, W1n, b1, nullptr, nullptr,
                                           h1b, nullptr);
    k_fused<true><<<NB, 512, 0, stream>>>((const uint4*)h1b, offs, csr,
                                          W2s, W2n, b2, Wfc, bfc,
                                          nullptr, out);
}

// Round 2
// 1244.144 us; speedup vs baseline: 1.5462x; 1.5462x over previous
//
#include <hip/hip_runtime.h>

#define NN 50000      // nodes
#define NE 800000     // edges
#define F  64         // feature dim
#define ATN 65        // NsT stride: 65 % 32 == 1 -> transposed agg stores spread all 32 banks (2-way, free)
#define SCAN_B 49     // scan blocks: 49 * 1024 >= 50000

typedef float f32x4 __attribute__((ext_vector_type(4)));

// bf16 round-to-nearest-even, returns low-16 bits
__device__ __forceinline__ unsigned bf16rne(float f) {
    unsigned u = __float_as_uint(f);
    return (u + 0x7fffu + ((u >> 16) & 1u)) >> 16;
}
__device__ __forceinline__ float bflo(unsigned p) { return __uint_as_float(p << 16); }
__device__ __forceinline__ float bfhi(unsigned p) { return __uint_as_float(p & 0xffff0000u); }

// ---------------- fused: edge degree count+slot  AND  embedding gather ----------------

__launch_bounds__(256)
__global__ void k_count_gather(const int* __restrict__ dst, int* __restrict__ cnt,
                               unsigned short* __restrict__ pos,
                               const float* __restrict__ embed, const int* __restrict__ ids,
                               uint2* __restrict__ xb) {
    int t = blockIdx.x * blockDim.x + threadIdx.x;
    if (t < NE) pos[t] = (unsigned short)atomicAdd(&cnt[dst[t]], 1);
    if (t < NN * 16) {
        int i = t >> 4, c = t & 15;
        float4 v = ((const float4*)embed)[ids[i] * 16 + c];
        uint2 p;
        p.x = bf16rne(v.x) | (bf16rne(v.y) << 16);
        p.y = bf16rne(v.z) | (bf16rne(v.w) << 16);
        xb[t] = p;
    }
}

// ---- 2-dispatch scan: block partials, then per-block redundant scan of partials ----

__launch_bounds__(256)
__global__ void k_scan_a(const int* __restrict__ cnt, int* __restrict__ partials) {
    __shared__ int sc[256];
    int t = threadIdx.x;
    int base = blockIdx.x * 1024 + t * 4;
    int s = 0;
#pragma unroll
    for (int k = 0; k < 4; ++k) {
        int idx = base + k;
        s += (idx < NN) ? cnt[idx] : 0;
    }
    sc[t] = s;
    __syncthreads();
    for (int d = 128; d > 0; d >>= 1) {
        if (t < d) sc[t] += sc[t + d];
        __syncthreads();
    }
    if (t == 0) partials[blockIdx.x] = sc[0];
}

__launch_bounds__(256)
__global__ void k_scan_c2(const int* __restrict__ cnt, const int* __restrict__ partials,
                          int* __restrict__ offs) {
    __shared__ int sboff;
    __shared__ int stotal;
    __shared__ int sc[256];
    int t = threadIdx.x;
    if (t < 64) {  // wave 0 redundantly scans the 49 partials
        int v = (t < SCAN_B) ? partials[t] : 0;
        int orig = v;
        for (int d = 1; d < 64; d <<= 1) {
            int u = __shfl_up(v, d);
            if (t >= d) v += u;
        }
        if (t == (int)blockIdx.x) sboff = v - orig;
        if (t == 63) stotal = v;
    }
    int base = blockIdx.x * 1024 + t * 4;
    int v4[4];
#pragma unroll
    for (int k = 0; k < 4; ++k) {
        int idx = base + k;
        v4[k] = (idx < NN) ? cnt[idx] : 0;
    }
    int lsum = v4[0] + v4[1] + v4[2] + v4[3];
    sc[t] = lsum;
    __syncthreads();
    for (int d = 1; d < 256; d <<= 1) {
        int u = (t >= d) ? sc[t - d] : 0;
        __syncthreads();
        sc[t] += u;
        __syncthreads();
    }
    int run = sboff + sc[t] - lsum;
#pragma unroll
    for (int k = 0; k < 4; ++k) {
        int idx = base + k;
        if (idx < NN) { offs[idx] = run; run += v4[k]; }
    }
    if (blockIdx.x == 0 && t == 0) offs[NN] = stotal;
}

// atomic-free fill: slot was precomputed in pos[]
__global__ void k_fill(const int* __restrict__ src, const int* __restrict__ dst,
                       const int* __restrict__ offs, const unsigned short* __restrict__ pos,
                       int* __restrict__ csr) {
    int e = blockIdx.x * blockDim.x + threadIdx.x;
    if (e < NE) csr[offs[dst[e]] + (int)pos[e]] = src[e];
}

// ---------------- fused layer: aggregate + GEMM in one kernel ----------------
// 512 threads, 64 nodes/block. Agg phase: thread = (node, uint4 chunk), 8 lanes
// per node, unroll-8 full-row (128 B) gathers with shfl-broadcast indices;
// result -> NsT (fp32). AsT removed from LDS — the GEMM phase streams the 64
// self rows straight from the bf16 global table (8 KB/block, 16-lane broadcast
// addresses, L1/L2-hot). LDS = NsT (stride 65, conflict-free) + Wpk = 33.0 KB.
// R1 POST-MORTEM: __launch_bounds__(512,8) capped VGPR at 64->32 and spilled
// the gather payload to scratch (FETCH 31MB->1.24GB, 18x slower). The live set
// is ~40 regs in the agg loop alone. Cap must stay ABOVE the live set:
// (512,4) -> 128 VGPRs, zero spill. Occupancy then 3-4 blocks/CU via LDS/VGPR.
// LAST=false: relu -> bf16 out. LAST=true: second GEMM with Wfc/bfc -> fp32 out
// (h2 tile reuses NsT, Wfc reuses Wpk storage).

__device__ __forceinline__ void add8(float s[8], const uint4 v) {
    s[0] += bflo(v.x); s[1] += bfhi(v.x);
    s[2] += bflo(v.y); s[3] += bfhi(v.y);
    s[4] += bflo(v.z); s[5] += bfhi(v.z);
    s[6] += bflo(v.w); s[7] += bfhi(v.w);
}

template <bool LAST>
__launch_bounds__(512, 4)
__global__ void k_fused(const uint4* __restrict__ Ab, const int* __restrict__ offs,
                        const int* __restrict__ csr,
                        const float* __restrict__ Ws, const float* __restrict__ Wn,
                        const float* __restrict__ b,
                        const float* __restrict__ Wfc, const float* __restrict__ bfc,
                        uint2* __restrict__ outb, float* __restrict__ out) {
    __shared__ alignas(16) float NsT[F * ATN];     // neighbor-mean tile, transposed [f][node]
    __shared__ alignas(16) unsigned Wpk[F * F];    // Ws|Wn<<16 bf16-packed [k][f]

    const int tid = threadIdx.x;
    const int node0 = blockIdx.x * 64;

    // stage packed weights
    for (int i = tid; i < F * F; i += 512)
        Wpk[i] = bf16rne(Ws[i]) | (bf16rne(Wn[i]) << 16);

    // agg: one (node, chunk) item per thread
    {
        const int n = tid >> 3;          // node within tile
        const int c = tid & 7;           // uint4 chunk (8 bf16 feats)
        const int lane = tid & 63;
        const int base = lane & 56;
        const int gnode = node0 + n;
        float s[8] = {0.f, 0.f, 0.f, 0.f, 0.f, 0.f, 0.f, 0.f};
        float inv = 0.f;
        if (gnode < NN) {
            int beg = offs[gnode], end = offs[gnode + 1];
            int j = beg;
            for (; j + 8 <= end; j += 8) {
                int v = csr[j + c];
                int i0 = __shfl(v, base + 0, 64), i1 = __shfl(v, base + 1, 64);
                int i2 = __shfl(v, base + 2, 64), i3 = __shfl(v, base + 3, 64);
                int i4 = __shfl(v, base + 4, 64), i5 = __shfl(v, base + 5, 64);
                int i6 = __shfl(v, base + 6, 64), i7 = __shfl(v, base + 7, 64);
                uint4 d0 = Ab[i0 * 8 + c], d1 = Ab[i1 * 8 + c];
                uint4 d2 = Ab[i2 * 8 + c], d3 = Ab[i3 * 8 + c];
                uint4 d4 = Ab[i4 * 8 + c], d5 = Ab[i5 * 8 + c];
                uint4 d6 = Ab[i6 * 8 + c], d7 = Ab[i7 * 8 + c];
                add8(s, d0); add8(s, d1); add8(s, d2); add8(s, d3);
                add8(s, d4); add8(s, d5); add8(s, d6); add8(s, d7);
            }
            int rem = end - j;
            if (rem > 0) {
                int v = csr[j + (c < rem ? c : 0)];
                int idx[8];
#pragma unroll
                for (int k = 0; k < 8; ++k) idx[k] = __shfl(v, base + k, 64);
#pragma unroll
                for (int k = 0; k < 8; ++k)
                    if (k < rem) { uint4 d = Ab[idx[k] * 8 + c]; add8(s, d); }
            }
            int deg = end - beg;
            inv = (deg > 0) ? 1.f / (float)deg : 0.f;
        }
        const int f = 8 * c;
#pragma unroll
        for (int q = 0; q < 8; ++q) NsT[(f + q) * ATN + n] = s[q] * inv;
    }
    __syncthreads();

    // GEMM: 512 threads = 16(feat-grp) x 32(node-grp); microtile 2 nodes x 4 feats
    // self operand streamed from global Ab (rows are L2/LLC-hot), 2-deep pipeline
    const int tx = tid & 15, ty = tid >> 4;
    const int rbase = (node0 + 2 * ty) * 8;   // uint4 index of this thread's first row
    float acc[2][4];
#pragma unroll
    for (int j = 0; j < 4; ++j) {
        float bv = b[4 * tx + j];
        acc[0][j] = bv; acc[1][j] = bv;
    }
    uint4 a0 = Ab[rbase];
    uint4 a1 = Ab[rbase + 8];
#pragma unroll
    for (int k8 = 0; k8 < 8; ++k8) {
        const uint4 p0 = a0, p1 = a1;
        if (k8 < 7) { a0 = Ab[rbase + k8 + 1]; a1 = Ab[rbase + 8 + k8 + 1]; }
        const float af0[8] = {bflo(p0.x), bfhi(p0.x), bflo(p0.y), bfhi(p0.y),
                              bflo(p0.z), bfhi(p0.z), bflo(p0.w), bfhi(p0.w)};
        const float af1[8] = {bflo(p1.x), bfhi(p1.x), bflo(p1.y), bfhi(p1.y),
                              bflo(p1.z), bfhi(p1.z), bflo(p1.w), bfhi(p1.w)};
#pragma unroll
        for (int kk = 0; kk < 8; ++kk) {
            const int k = 8 * k8 + kk;
            float nx = NsT[k * ATN + 2 * ty];
            float ny = NsT[k * ATN + 2 * ty + 1];
            uint4 wq = *(const uint4*)&Wpk[k * 64 + 4 * tx];
            float ws_[4] = {bflo(wq.x), bflo(wq.y), bflo(wq.z), bflo(wq.w)};
            float wn_[4] = {bfhi(wq.x), bfhi(wq.y), bfhi(wq.z), bfhi(wq.w)};
#pragma unroll
            for (int j = 0; j < 4; ++j) {
                acc[0][j] += af0[kk] * ws_[j] + nx * wn_[j];
                acc[1][j] += af1[kk] * ws_[j] + ny * wn_[j];
            }
        }
    }

    if (!LAST) {
#pragma unroll
        for (int i = 0; i < 2; ++i) {
            int node = node0 + 2 * ty + i;
            if (node < NN) {
                float o0 = acc[i][0] > 0.f ? acc[i][0] : 0.f;
                float o1 = acc[i][1] > 0.f ? acc[i][1] : 0.f;
                float o2 = acc[i][2] > 0.f ? acc[i][2] : 0.f;
                float o3 = acc[i][3] > 0.f ? acc[i][3] : 0.f;
                uint2 p;
                p.x = bf16rne(o0) | (bf16rne(o1) << 16);
                p.y = bf16rne(o2) | (bf16rne(o3) << 16);
                outb[node * 16 + tx] = p;
            }
        }
    } else {
        // fused final GEMM: h2 tile -> NsT (reused); Wfc (fp32) reuses Wpk storage
        __syncthreads();
        float* Wf = (float*)Wpk;
#pragma unroll
        for (int i = 0; i < 2; ++i)
#pragma unroll
            for (int j = 0; j < 4; ++j)
                NsT[(4 * tx + j) * ATN + (2 * ty + i)] = acc[i][j];
        for (int i = tid; i < F * F / 4; i += 512)
            ((float4*)Wf)[i] = ((const float4*)Wfc)[i];
        __syncthreads();

        float acc2[2][4];
#pragma unroll
        for (int j = 0; j < 4; ++j) {
            float bv = bfc[4 * tx + j];
            acc2[0][j] = bv; acc2[1][j] = bv;
        }
#pragma unroll 4
        for (int k = 0; k < 64; ++k) {
            float ax = NsT[k * ATN + 2 * ty];
            float ay = NsT[k * ATN + 2 * ty + 1];
            float4 w4 = *(const float4*)&Wf[k * 64 + 4 * tx];
            float w_[4] = {w4.x, w4.y, w4.z, w4.w};
#pragma unroll
            for (int j = 0; j < 4; ++j) {
                acc2[0][j] += ax * w_[j];
                acc2[1][j] += ay * w_[j];
            }
        }
#pragma unroll
        for (int i = 0; i < 2; ++i) {
            int node = node0 + 2 * ty + i;
            if (node < NN) {
                f32x4 o;
                o.x = acc2[i][0]; o.y = acc2[i][1]; o.z = acc2[i][2]; o.w = acc2[i][3];
                __builtin_nontemporal_store(o, (f32x4*)&out[node * 64 + 4 * tx]);
            }
        }
    }
}

// ---------------- launch ----------------

extern "C" void kernel_launch(void* const* d_in, const int* in_sizes, int n_in,
                              void* d_out, int out_size, void* d_ws, size_t ws_size,
                              hipStream_t stream) {
    const float* embed = (const float*)d_in[0];
    const float* W1s = (const float*)d_in[1];
    const float* W1n = (const float*)d_in[2];
    const float* b1  = (const float*)d_in[3];
    const float* W2s = (const float*)d_in[4];
    const float* W2n = (const float*)d_in[5];
    const float* b2  = (const float*)d_in[6];
    const float* Wfc = (const float*)d_in[7];
    const float* bfc = (const float*)d_in[8];
    const int* ids = (const int*)d_in[9];
    const int* src = (const int*)d_in[10];
    const int* dst = (const int*)d_in[11];
    float* out = (float*)d_out;

    char* ws = (char*)d_ws;
    size_t off = 0;
    auto alloc = [&](size_t nb) {
        char* p = ws + off;
        off = (off + nb + 255) & ~(size_t)255;
        return p;
    };
    int*   cnt      = (int*)alloc(NN * sizeof(int));        // zeroed
    size_t zero_bytes = off;
    int*   offs     = (int*)alloc((NN + 1) * sizeof(int));
    int*   partials = (int*)alloc(SCAN_B * sizeof(int));
    unsigned short* pos = (unsigned short*)alloc(NE * sizeof(unsigned short));
    int*   csr      = (int*)alloc(NE * sizeof(int));
    // +64 rows pad: GEMM self-row streaming reads up to node 50047 (benign garbage, stores guarded)
    uint2* xb       = (uint2*)alloc((size_t)(NN + 64) * 16 * sizeof(uint2));  // bf16 x
    uint2* h1b      = (uint2*)alloc((size_t)(NN + 64) * 16 * sizeof(uint2));  // bf16 h1

    hipMemsetAsync(d_ws, 0, zero_bytes, stream);

    const int TB = 256;
    const int EB = (NE + TB - 1) / TB;     // 3125
    k_count_gather<<<EB, TB, 0, stream>>>(dst, cnt, pos, embed, ids, xb);
    k_scan_a<<<SCAN_B, 256, 0, stream>>>(cnt, partials);
    k_scan_c2<<<SCAN_B, 256, 0, stream>>>(cnt, partials, offs);
    k_fill<<<EB, TB, 0, stream>>>(src, dst, offs, pos, csr);

    const int NB = (NN + 63) / 64;         // 782
    k_fused<false><<<NB, 512, 0, stream>>>((const uint4*)xb, offs, csr,
                                           W1s, W1n, b1, nullptr, nullptr,
                                           h1b, nullptr);
    k_fused<true><<<NB, 512, 0, stream>>>((const uint4*)h1b, offs, csr,
                                          W2s, W2n, b2, Wfc, bfc,
                                          nullptr, out);
}

// Round 3
// 232.601 us; speedup vs baseline: 8.2704x; 5.3488x over previous
//
#include <hip/hip_runtime.h>

#define NN 50000      // nodes
#define NE 800000     // edges
#define F  64         // feature dim
#define SCAN_B 49     // scan blocks: 49 * 1024 >= 50000

typedef float f32x4 __attribute__((ext_vector_type(4)));

// bf16 round-to-nearest-even, returns low-16 bits
__device__ __forceinline__ unsigned bf16rne(float f) {
    unsigned u = __float_as_uint(f);
    return (u + 0x7fffu + ((u >> 16) & 1u)) >> 16;
}
__device__ __forceinline__ float bflo(unsigned p) { return __uint_as_float(p << 16); }
__device__ __forceinline__ float bfhi(unsigned p) { return __uint_as_float(p & 0xffff0000u); }

// XOR-swizzled column index for the [feat][node] LDS tiles (stride 64, no pad).
// Stores from the agg phase have lanes = (n 0..7) x (c 0..7); XOR-ing bits 3..4
// of the node column with (c&3) spreads the 64 lanes across all 32 banks
// (2-way = free). Swizzle bits are >= bit3, so n, n+1 stay adjacent (float2 ok).
__device__ __forceinline__ int nswz(int f, int n) { return f * 64 + (n ^ (((f >> 3) & 3) << 3)); }
// Apk rows are k-pairs: r = k>>1 in [0,32); its c is r>>2.
__device__ __forceinline__ int aswz(int r, int n) { return r * 64 + (n ^ (((r >> 2) & 3) << 3)); }

// ---------------- fused: edge degree count+slot  AND  embedding gather ----------------

__launch_bounds__(256)
__global__ void k_count_gather(const int* __restrict__ dst, int* __restrict__ cnt,
                               unsigned short* __restrict__ pos,
                               const float* __restrict__ embed, const int* __restrict__ ids,
                               uint2* __restrict__ xb) {
    int t = blockIdx.x * blockDim.x + threadIdx.x;
    if (t < NE) pos[t] = (unsigned short)atomicAdd(&cnt[dst[t]], 1);
    if (t < NN * 16) {
        int i = t >> 4, c = t & 15;
        float4 v = ((const float4*)embed)[ids[i] * 16 + c];
        uint2 p;
        p.x = bf16rne(v.x) | (bf16rne(v.y) << 16);
        p.y = bf16rne(v.z) | (bf16rne(v.w) << 16);
        xb[t] = p;
    }
}

// ---- 2-dispatch scan: block partials, then per-block redundant scan of partials ----

__launch_bounds__(256)
__global__ void k_scan_a(const int* __restrict__ cnt, int* __restrict__ partials) {
    __shared__ int sc[256];
    int t = threadIdx.x;
    int base = blockIdx.x * 1024 + t * 4;
    int s = 0;
#pragma unroll
    for (int k = 0; k < 4; ++k) {
        int idx = base + k;
        s += (idx < NN) ? cnt[idx] : 0;
    }
    sc[t] = s;
    __syncthreads();
    for (int d = 128; d > 0; d >>= 1) {
        if (t < d) sc[t] += sc[t + d];
        __syncthreads();
    }
    if (t == 0) partials[blockIdx.x] = sc[0];
}

__launch_bounds__(256)
__global__ void k_scan_c2(const int* __restrict__ cnt, const int* __restrict__ partials,
                          int* __restrict__ offs) {
    __shared__ int sboff;
    __shared__ int stotal;
    __shared__ int sc[256];
    int t = threadIdx.x;
    if (t < 64) {  // wave 0 redundantly scans the 49 partials
        int v = (t < SCAN_B) ? partials[t] : 0;
        int orig = v;
        for (int d = 1; d < 64; d <<= 1) {
            int u = __shfl_up(v, d);
            if (t >= d) v += u;
        }
        if (t == (int)blockIdx.x) sboff = v - orig;
        if (t == 63) stotal = v;
    }
    int base = blockIdx.x * 1024 + t * 4;
    int v4[4];
#pragma unroll
    for (int k = 0; k < 4; ++k) {
        int idx = base + k;
        v4[k] = (idx < NN) ? cnt[idx] : 0;
    }
    int lsum = v4[0] + v4[1] + v4[2] + v4[3];
    sc[t] = lsum;
    __syncthreads();
    for (int d = 1; d < 256; d <<= 1) {
        int u = (t >= d) ? sc[t - d] : 0;
        __syncthreads();
        sc[t] += u;
        __syncthreads();
    }
    int run = sboff + sc[t] - lsum;
#pragma unroll
    for (int k = 0; k < 4; ++k) {
        int idx = base + k;
        if (idx < NN) { offs[idx] = run; run += v4[k]; }
    }
    if (blockIdx.x == 0 && t == 0) offs[NN] = stotal;
}

// atomic-free fill: slot was precomputed in pos[]
__global__ void k_fill(const int* __restrict__ src, const int* __restrict__ dst,
                       const int* __restrict__ offs, const unsigned short* __restrict__ pos,
                       int* __restrict__ csr) {
    int e = blockIdx.x * blockDim.x + threadIdx.x;
    if (e < NE) csr[offs[dst[e]] + (int)pos[e]] = src[e];
}

// ---------------- fused layer: aggregate + GEMM in one kernel ----------------
// 512 threads, 64 nodes/block. Agg phase: thread = (node, uint4 chunk), 8 lanes
// per node, unroll-8 full-row (128 B) gathers with shfl-broadcast indices;
// neighbor sums -> NsT (fp32, swizzled). Self rows stored bf16-packed (Apk,
// lossless: table is already bf16 pairs) -> LDS is EXACTLY 40960 B
// (NsT 16K + Apk 8K + Wpk 16K) -> 4 blocks/CU (was 3 at 51.2 KB).
// R1/R2 POST-MORTEM: __launch_bounds__ min-occupancy arg clamped VGPR to 64->
// spilled the gather payload (FETCH 31MB -> 1GB, 16-18x slower). The live set
// is ~80 regs. NO occupancy clamp; R0 evidence: unclamped build = 52 VGPR,
// zero spill, which permits 8 waves/SIMD -> the 4-block LDS budget is usable.
// Bank conflicts: XOR swizzle on the node column (2.1M -> ~100K proven by the
// stride-65 equivalent in R2).
// LAST=false: relu -> bf16 out. LAST=true: second GEMM with Wfc/bfc -> fp32 out
// (h2 tile reuses NsT, Wfc reuses Wpk storage).

__device__ __forceinline__ void add8(float s[8], const uint4 v) {
    s[0] += bflo(v.x); s[1] += bfhi(v.x);
    s[2] += bflo(v.y); s[3] += bfhi(v.y);
    s[4] += bflo(v.z); s[5] += bfhi(v.z);
    s[6] += bflo(v.w); s[7] += bfhi(v.w);
}

template <bool LAST>
__launch_bounds__(512)
__global__ void k_fused(const uint4* __restrict__ Ab, const int* __restrict__ offs,
                        const int* __restrict__ csr,
                        const float* __restrict__ Ws, const float* __restrict__ Wn,
                        const float* __restrict__ b,
                        const float* __restrict__ Wfc, const float* __restrict__ bfc,
                        uint2* __restrict__ outb, float* __restrict__ out) {
    __shared__ alignas(16) float    NsT[F * 64];   // neighbor-mean tile [f][node^swz], fp32
    __shared__ alignas(16) unsigned Apk[32 * 64];  // self tile, bf16 k-pairs [k>>1][node^swz]
    __shared__ alignas(16) unsigned Wpk[F * F];    // Ws|Wn<<16 bf16-packed [k][f], linear

    const int tid = threadIdx.x;
    const int node0 = blockIdx.x * 64;

    // stage packed weights
    for (int i = tid; i < F * F; i += 512)
        Wpk[i] = bf16rne(Ws[i]) | (bf16rne(Wn[i]) << 16);

    // agg: one (node, chunk) item per thread
    {
        const int n = tid >> 3;          // node within tile
        const int c = tid & 7;           // uint4 chunk (8 bf16 feats)
        const int lane = tid & 63;
        const int base = lane & 56;
        const int gnode = node0 + n;
        float s[8] = {0.f, 0.f, 0.f, 0.f, 0.f, 0.f, 0.f, 0.f};
        uint4 a = make_uint4(0u, 0u, 0u, 0u);
        float inv = 0.f;
        if (gnode < NN) {
            a = Ab[gnode * 8 + c];
            int beg = offs[gnode], end = offs[gnode + 1];
            int j = beg;
            for (; j + 8 <= end; j += 8) {
                int v = csr[j + c];
                int i0 = __shfl(v, base + 0, 64), i1 = __shfl(v, base + 1, 64);
                int i2 = __shfl(v, base + 2, 64), i3 = __shfl(v, base + 3, 64);
                int i4 = __shfl(v, base + 4, 64), i5 = __shfl(v, base + 5, 64);
                int i6 = __shfl(v, base + 6, 64), i7 = __shfl(v, base + 7, 64);
                uint4 d0 = Ab[i0 * 8 + c], d1 = Ab[i1 * 8 + c];
                uint4 d2 = Ab[i2 * 8 + c], d3 = Ab[i3 * 8 + c];
                uint4 d4 = Ab[i4 * 8 + c], d5 = Ab[i5 * 8 + c];
                uint4 d6 = Ab[i6 * 8 + c], d7 = Ab[i7 * 8 + c];
                add8(s, d0); add8(s, d1); add8(s, d2); add8(s, d3);
                add8(s, d4); add8(s, d5); add8(s, d6); add8(s, d7);
            }
            int rem = end - j;
            if (rem > 0) {
                int v = csr[j + (c < rem ? c : 0)];
                int idx[8];
#pragma unroll
                for (int k = 0; k < 8; ++k) idx[k] = __shfl(v, base + k, 64);
#pragma unroll
                for (int k = 0; k < 8; ++k)
                    if (k < rem) { uint4 d = Ab[idx[k] * 8 + c]; add8(s, d); }
            }
            int deg = end - beg;
            inv = (deg > 0) ? 1.f / (float)deg : 0.f;
        }
        const int f = 8 * c;
        // self row: store the bf16 pairs as-is (lossless, 4 stores)
        Apk[aswz(4 * c + 0, n)] = a.x;
        Apk[aswz(4 * c + 1, n)] = a.y;
        Apk[aswz(4 * c + 2, n)] = a.z;
        Apk[aswz(4 * c + 3, n)] = a.w;
#pragma unroll
        for (int q = 0; q < 8; ++q) NsT[nswz(f + q, n)] = s[q] * inv;
    }
    __syncthreads();

    // GEMM: 512 threads = 16(feat-grp) x 32(node-grp); microtile 2 nodes x 4 feats
    const int tx = tid & 15, ty = tid >> 4;
    float acc[2][4];
#pragma unroll
    for (int j = 0; j < 4; ++j) {
        float bv = b[4 * tx + j];
        acc[0][j] = bv; acc[1][j] = bv;
    }
#pragma unroll 4
    for (int r = 0; r < 32; ++r) {          // k-pair index, k = 2r, 2r+1
        const int k0 = 2 * r;
        uint2  ap = *(const uint2*)&Apk[aswz(r, 2 * ty)];
        float2 n0 = *(const float2*)&NsT[nswz(k0, 2 * ty)];
        float2 n1 = *(const float2*)&NsT[nswz(k0 + 1, 2 * ty)];
        uint4  w0 = *(const uint4*)&Wpk[k0 * 64 + 4 * tx];
        uint4  w1 = *(const uint4*)&Wpk[(k0 + 1) * 64 + 4 * tx];
        // node 2ty: feats k0,k0+1 ; node 2ty+1: same
        const float a00 = bflo(ap.x), a01 = bfhi(ap.x);
        const float a10 = bflo(ap.y), a11 = bfhi(ap.y);
        const float ws0[4] = {bflo(w0.x), bflo(w0.y), bflo(w0.z), bflo(w0.w)};
        const float wn0[4] = {bfhi(w0.x), bfhi(w0.y), bfhi(w0.z), bfhi(w0.w)};
        const float ws1[4] = {bflo(w1.x), bflo(w1.y), bflo(w1.z), bflo(w1.w)};
        const float wn1[4] = {bfhi(w1.x), bfhi(w1.y), bfhi(w1.z), bfhi(w1.w)};
#pragma unroll
        for (int j = 0; j < 4; ++j) {
            acc[0][j] += a00 * ws0[j] + n0.x * wn0[j];
            acc[1][j] += a10 * ws0[j] + n0.y * wn0[j];
        }
#pragma unroll
        for (int j = 0; j < 4; ++j) {
            acc[0][j] += a01 * ws1[j] + n1.x * wn1[j];
            acc[1][j] += a11 * ws1[j] + n1.y * wn1[j];
        }
    }

    if (!LAST) {
#pragma unroll
        for (int i = 0; i < 2; ++i) {
            int node = node0 + 2 * ty + i;
            if (node < NN) {
                float o0 = acc[i][0] > 0.f ? acc[i][0] : 0.f;
                float o1 = acc[i][1] > 0.f ? acc[i][1] : 0.f;
                float o2 = acc[i][2] > 0.f ? acc[i][2] : 0.f;
                float o3 = acc[i][3] > 0.f ? acc[i][3] : 0.f;
                uint2 p;
                p.x = bf16rne(o0) | (bf16rne(o1) << 16);
                p.y = bf16rne(o2) | (bf16rne(o3) << 16);
                outb[node * 16 + tx] = p;
            }
        }
    } else {
        // fused final GEMM: h2 tile -> NsT (reused, swizzled); Wfc reuses Wpk storage
        __syncthreads();
        float* Wf = (float*)Wpk;
#pragma unroll
        for (int i = 0; i < 2; ++i)
#pragma unroll
            for (int j = 0; j < 4; ++j)
                NsT[nswz(4 * tx + j, 2 * ty + i)] = acc[i][j];
        for (int i = tid; i < F * F / 4; i += 512)
            ((float4*)Wf)[i] = ((const float4*)Wfc)[i];
        __syncthreads();

        float acc2[2][4];
#pragma unroll
        for (int j = 0; j < 4; ++j) {
            float bv = bfc[4 * tx + j];
            acc2[0][j] = bv; acc2[1][j] = bv;
        }
#pragma unroll 4
        for (int k = 0; k < 64; ++k) {
            float2 a2 = *(const float2*)&NsT[nswz(k, 2 * ty)];
            float4 w4 = *(const float4*)&Wf[k * 64 + 4 * tx];
            float w_[4] = {w4.x, w4.y, w4.z, w4.w};
#pragma unroll
            for (int j = 0; j < 4; ++j) {
                acc2[0][j] += a2.x * w_[j];
                acc2[1][j] += a2.y * w_[j];
            }
        }
#pragma unroll
        for (int i = 0; i < 2; ++i) {
            int node = node0 + 2 * ty + i;
            if (node < NN) {
                f32x4 o;
                o.x = acc2[i][0]; o.y = acc2[i][1]; o.z = acc2[i][2]; o.w = acc2[i][3];
                __builtin_nontemporal_store(o, (f32x4*)&out[node * 64 + 4 * tx]);
            }
        }
    }
}

// ---------------- launch ----------------

extern "C" void kernel_launch(void* const* d_in, const int* in_sizes, int n_in,
                              void* d_out, int out_size, void* d_ws, size_t ws_size,
                              hipStream_t stream) {
    const float* embed = (const float*)d_in[0];
    const float* W1s = (const float*)d_in[1];
    const float* W1n = (const float*)d_in[2];
    const float* b1  = (const float*)d_in[3];
    const float* W2s = (const float*)d_in[4];
    const float* W2n = (const float*)d_in[5];
    const float* b2  = (const float*)d_in[6];
    const float* Wfc = (const float*)d_in[7];
    const float* bfc = (const float*)d_in[8];
    const int* ids = (const int*)d_in[9];
    const int* src = (const int*)d_in[10];
    const int* dst = (const int*)d_in[11];
    float* out = (float*)d_out;

    char* ws = (char*)d_ws;
    size_t off = 0;
    auto alloc = [&](size_t nb) {
        char* p = ws + off;
        off = (off + nb + 255) & ~(size_t)255;
        return p;
    };
    int*   cnt      = (int*)alloc(NN * sizeof(int));        // zeroed
    size_t zero_bytes = off;
    int*   offs     = (int*)alloc((NN + 1) * sizeof(int));
    int*   partials = (int*)alloc(SCAN_B * sizeof(int));
    unsigned short* pos = (unsigned short*)alloc(NE * sizeof(unsigned short));
    int*   csr      = (int*)alloc(NE * sizeof(int));
    uint2* xb       = (uint2*)alloc((size_t)NN * 16 * sizeof(uint2));  // bf16 x
    uint2* h1b      = (uint2*)alloc((size_t)NN * 16 * sizeof(uint2));  // bf16 h1

    hipMemsetAsync(d_ws, 0, zero_bytes, stream);

    const int TB = 256;
    const int EB = (NE + TB - 1) / TB;     // 3125
    k_count_gather<<<EB, TB, 0, stream>>>(dst, cnt, pos, embed, ids, xb);
    k_scan_a<<<SCAN_B, 256, 0, stream>>>(cnt, partials);
    k_scan_c2<<<SCAN_B, 256, 0, stream>>>(cnt, partials, offs);
    k_fill<<<EB, TB, 0, stream>>>(src, dst, offs, pos, csr);

    const int NB = (NN + 63) / 64;         // 782
    k_fused<false><<<NB, 512, 0, stream>>>((const uint4*)xb, offs, csr,
                                           W1s, W1n, b1, nullptr, nullptr,
                                           h1b, nullptr);
    k_fused<true><<<NB, 512, 0, stream>>>((const uint4*)h1b, offs, csr,
                                          W2s, W2n, b2, Wfc, bfc,
                                          nullptr, out);
}

// Round 4
// 217.149 us; speedup vs baseline: 8.8589x; 1.0712x over previous
//
#include <hip/hip_runtime.h>

#define NN 50000      // nodes
#define NE 800000     // edges
#define F  64         // feature dim
#define SCAN_B 49     // scan blocks: 49 * 1024 >= 50000

typedef float f32x4 __attribute__((ext_vector_type(4)));
typedef float f32x2 __attribute__((ext_vector_type(2)));

// bf16 round-to-nearest-even, returns low-16 bits
__device__ __forceinline__ unsigned bf16rne(float f) {
    unsigned u = __float_as_uint(f);
    return (u + 0x7fffu + ((u >> 16) & 1u)) >> 16;
}
__device__ __forceinline__ float bflo(unsigned p) { return __uint_as_float(p << 16); }
__device__ __forceinline__ float bfhi(unsigned p) { return __uint_as_float(p & 0xffff0000u); }
// unpack a bf16 pair to f32x2 {lo, hi} — feeds v_pk_add_f32 / v_pk_fma_f32
__device__ __forceinline__ f32x2 up2(unsigned p) {
    f32x2 r;
    r.x = __uint_as_float(p << 16);
    r.y = __uint_as_float(p & 0xffff0000u);
    return r;
}

// XOR-swizzled column index for the [feat][node] LDS tiles (stride 64, no pad).
// Agg-phase store lanes are (n 0..7) x (c 0..7); XOR-ing bits 3..4 of the node
// column with (c&3) spreads 64 lanes across all 32 banks (2-way = free).
// Swizzle bits >= bit3 keep n, n+1 adjacent (float2/uint2 reads ok).
__device__ __forceinline__ int nswz(int f, int n) { return f * 64 + (n ^ (((f >> 3) & 3) << 3)); }
__device__ __forceinline__ int aswz(int r, int n) { return r * 64 + (n ^ (((r >> 2) & 3) << 3)); }

// ---------------- fused: edge degree count+slot  AND  embedding gather ----------------

__launch_bounds__(256)
__global__ void k_count_gather(const int* __restrict__ dst, int* __restrict__ cnt,
                               unsigned short* __restrict__ pos,
                               const float* __restrict__ embed, const int* __restrict__ ids,
                               uint2* __restrict__ xb) {
    int t = blockIdx.x * blockDim.x + threadIdx.x;
    if (t < NE) pos[t] = (unsigned short)atomicAdd(&cnt[dst[t]], 1);
    if (t < NN * 16) {
        int i = t >> 4, c = t & 15;
        float4 v = ((const float4*)embed)[ids[i] * 16 + c];
        uint2 p;
        p.x = bf16rne(v.x) | (bf16rne(v.y) << 16);
        p.y = bf16rne(v.z) | (bf16rne(v.w) << 16);
        xb[t] = p;
    }
}

// ---- 2-dispatch scan: block partials, then per-block redundant scan of partials ----

__launch_bounds__(256)
__global__ void k_scan_a(const int* __restrict__ cnt, int* __restrict__ partials) {
    __shared__ int sc[256];
    int t = threadIdx.x;
    int base = blockIdx.x * 1024 + t * 4;
    int s = 0;
#pragma unroll
    for (int k = 0; k < 4; ++k) {
        int idx = base + k;
        s += (idx < NN) ? cnt[idx] : 0;
    }
    sc[t] = s;
    __syncthreads();
    for (int d = 128; d > 0; d >>= 1) {
        if (t < d) sc[t] += sc[t + d];
        __syncthreads();
    }
    if (t == 0) partials[blockIdx.x] = sc[0];
}

__launch_bounds__(256)
__global__ void k_scan_c2(const int* __restrict__ cnt, const int* __restrict__ partials,
                          int* __restrict__ offs) {
    __shared__ int sboff;
    __shared__ int stotal;
    __shared__ int sc[256];
    int t = threadIdx.x;
    if (t < 64) {  // wave 0 redundantly scans the 49 partials
        int v = (t < SCAN_B) ? partials[t] : 0;
        int orig = v;
        for (int d = 1; d < 64; d <<= 1) {
            int u = __shfl_up(v, d);
            if (t >= d) v += u;
        }
        if (t == (int)blockIdx.x) sboff = v - orig;
        if (t == 63) stotal = v;
    }
    int base = blockIdx.x * 1024 + t * 4;
    int v4[4];
#pragma unroll
    for (int k = 0; k < 4; ++k) {
        int idx = base + k;
        v4[k] = (idx < NN) ? cnt[idx] : 0;
    }
    int lsum = v4[0] + v4[1] + v4[2] + v4[3];
    sc[t] = lsum;
    __syncthreads();
    for (int d = 1; d < 256; d <<= 1) {
        int u = (t >= d) ? sc[t - d] : 0;
        __syncthreads();
        sc[t] += u;
        __syncthreads();
    }
    int run = sboff + sc[t] - lsum;
#pragma unroll
    for (int k = 0; k < 4; ++k) {
        int idx = base + k;
        if (idx < NN) { offs[idx] = run; run += v4[k]; }
    }
    if (blockIdx.x == 0 && t == 0) offs[NN] = stotal;
}

// atomic-free fill: slot was precomputed in pos[]. csr is ushort (src < 65536):
// halves the random-scatter footprint (3.2 -> 1.6 MB) and the per-layer csr read.
__global__ void k_fill(const int* __restrict__ src, const int* __restrict__ dst,
                       const int* __restrict__ offs, const unsigned short* __restrict__ pos,
                       unsigned short* __restrict__ csr) {
    int e = blockIdx.x * blockDim.x + threadIdx.x;
    if (e < NE) csr[offs[dst[e]] + (int)pos[e]] = (unsigned short)src[e];
}

// ---------------- fused layer: aggregate + GEMM in one kernel ----------------
// 512 threads, 64 nodes/block. Agg phase: thread = (node, uint4 chunk), 8 lanes
// per node, unroll-8 full-row (128 B) gathers with shfl-broadcast indices;
// neighbor sums in f32x2 pairs (v_pk_add_f32) -> NsT (fp32, swizzled). Self rows
// stored bf16-packed (Apk, lossless). LDS = 40960 B (NsT 16K + Apk 8K + Wpk 16K).
// GEMM microtile 2 nodes x 4 feats with f32x2 accumulators (v_pk_fma_f32).
// R3 POST-MORTEM: grid is 782 blocks = 3.05/CU, so occupancy capacity >3 is
// unusable; conflicts at 450K are noise. The agg gather path is the binding
// constraint -> this round cuts VALU/byte (pk math) and csr bytes (ushort).
// NO __launch_bounds__ occupancy clamp (R1/R2: clamping below the ~80-reg live
// set spilled the gather payload, 16-18x slower).

__device__ __forceinline__ void add8(f32x2 s[4], const uint4 v) {
    s[0] += up2(v.x);
    s[1] += up2(v.y);
    s[2] += up2(v.z);
    s[3] += up2(v.w);
}

template <bool LAST>
__launch_bounds__(512)
__global__ void k_fused(const uint4* __restrict__ Ab, const int* __restrict__ offs,
                        const unsigned short* __restrict__ csr,
                        const float* __restrict__ Ws, const float* __restrict__ Wn,
                        const float* __restrict__ b,
                        const float* __restrict__ Wfc, const float* __restrict__ bfc,
                        uint2* __restrict__ outb, float* __restrict__ out) {
    __shared__ alignas(16) float    NsT[F * 64];   // neighbor-mean tile [f][node^swz], fp32
    __shared__ alignas(16) unsigned Apk[32 * 64];  // self tile, bf16 k-pairs [k>>1][node^swz]
    __shared__ alignas(16) unsigned Wpk[F * F];    // Ws|Wn<<16 bf16-packed [k][f], linear

    const int tid = threadIdx.x;
    const int node0 = blockIdx.x * 64;

    // stage packed weights
    for (int i = tid; i < F * F; i += 512)
        Wpk[i] = bf16rne(Ws[i]) | (bf16rne(Wn[i]) << 16);

    // agg: one (node, chunk) item per thread
    {
        const int n = tid >> 3;          // node within tile
        const int c = tid & 7;           // uint4 chunk (8 bf16 feats)
        const int lane = tid & 63;
        const int base = lane & 56;
        const int gnode = node0 + n;
        f32x2 s[4];
        s[0] = 0.f; s[1] = 0.f; s[2] = 0.f; s[3] = 0.f;
        uint4 a = make_uint4(0u, 0u, 0u, 0u);
        float inv = 0.f;
        if (gnode < NN) {
            a = Ab[gnode * 8 + c];
            int beg = offs[gnode], end = offs[gnode + 1];
            int j = beg;
            for (; j + 8 <= end; j += 8) {
                int v = (int)csr[j + c];
                int i0 = __shfl(v, base + 0, 64), i1 = __shfl(v, base + 1, 64);
                int i2 = __shfl(v, base + 2, 64), i3 = __shfl(v, base + 3, 64);
                int i4 = __shfl(v, base + 4, 64), i5 = __shfl(v, base + 5, 64);
                int i6 = __shfl(v, base + 6, 64), i7 = __shfl(v, base + 7, 64);
                uint4 d0 = Ab[i0 * 8 + c], d1 = Ab[i1 * 8 + c];
                uint4 d2 = Ab[i2 * 8 + c], d3 = Ab[i3 * 8 + c];
                uint4 d4 = Ab[i4 * 8 + c], d5 = Ab[i5 * 8 + c];
                uint4 d6 = Ab[i6 * 8 + c], d7 = Ab[i7 * 8 + c];
                add8(s, d0); add8(s, d1); add8(s, d2); add8(s, d3);
                add8(s, d4); add8(s, d5); add8(s, d6); add8(s, d7);
            }
            int rem = end - j;
            if (rem > 0) {
                int v = (int)csr[j + (c < rem ? c : 0)];
                int idx[8];
#pragma unroll
                for (int k = 0; k < 8; ++k) idx[k] = __shfl(v, base + k, 64);
#pragma unroll
                for (int k = 0; k < 8; ++k)
                    if (k < rem) { uint4 d = Ab[idx[k] * 8 + c]; add8(s, d); }
            }
            int deg = end - beg;
            inv = (deg > 0) ? 1.f / (float)deg : 0.f;
        }
        const int f = 8 * c;
        // self row: store the bf16 pairs as-is (lossless, 4 stores)
        Apk[aswz(4 * c + 0, n)] = a.x;
        Apk[aswz(4 * c + 1, n)] = a.y;
        Apk[aswz(4 * c + 2, n)] = a.z;
        Apk[aswz(4 * c + 3, n)] = a.w;
#pragma unroll
        for (int q = 0; q < 4; ++q) {
            NsT[nswz(f + 2 * q + 0, n)] = s[q].x * inv;
            NsT[nswz(f + 2 * q + 1, n)] = s[q].y * inv;
        }
    }
    __syncthreads();

    // GEMM: 512 threads = 16(feat-grp) x 32(node-grp); microtile 2 nodes x 4 feats
    // f32x2 accumulators: acc[node][fp] covers feats 4tx+2fp, 4tx+2fp+1
    const int tx = tid & 15, ty = tid >> 4;
    f32x2 acc[2][2];
    {
        f32x2 b01, b23;
        b01.x = b[4 * tx + 0]; b01.y = b[4 * tx + 1];
        b23.x = b[4 * tx + 2]; b23.y = b[4 * tx + 3];
        acc[0][0] = b01; acc[0][1] = b23;
        acc[1][0] = b01; acc[1][1] = b23;
    }
#pragma unroll 4
    for (int r = 0; r < 32; ++r) {          // k-pair index, k = 2r, 2r+1
        const int k0 = 2 * r;
        uint2  ap = *(const uint2*)&Apk[aswz(r, 2 * ty)];
        float2 n0 = *(const float2*)&NsT[nswz(k0, 2 * ty)];
        float2 n1 = *(const float2*)&NsT[nswz(k0 + 1, 2 * ty)];
        uint4  w0 = *(const uint4*)&Wpk[k0 * 64 + 4 * tx];
        uint4  w1 = *(const uint4*)&Wpk[(k0 + 1) * 64 + 4 * tx];
        // weight pairs over adjacent output feats
        f32x2 ws0A, ws0B, wn0A, wn0B, ws1A, ws1B, wn1A, wn1B;
        ws0A.x = bflo(w0.x); ws0A.y = bflo(w0.y); ws0B.x = bflo(w0.z); ws0B.y = bflo(w0.w);
        wn0A.x = bfhi(w0.x); wn0A.y = bfhi(w0.y); wn0B.x = bfhi(w0.z); wn0B.y = bfhi(w0.w);
        ws1A.x = bflo(w1.x); ws1A.y = bflo(w1.y); ws1B.x = bflo(w1.z); ws1B.y = bflo(w1.w);
        wn1A.x = bfhi(w1.x); wn1A.y = bfhi(w1.y); wn1B.x = bfhi(w1.z); wn1B.y = bfhi(w1.w);
        // self operands: node 2ty feats k0,k0+1 in ap.x; node 2ty+1 in ap.y
        const float a00 = bflo(ap.x), a01 = bfhi(ap.x);
        const float a10 = bflo(ap.y), a11 = bfhi(ap.y);
        acc[0][0] += a00 * ws0A + n0.x * wn0A;
        acc[0][1] += a00 * ws0B + n0.x * wn0B;
        acc[1][0] += a10 * ws0A + n0.y * wn0A;
        acc[1][1] += a10 * ws0B + n0.y * wn0B;
        acc[0][0] += a01 * ws1A + n1.x * wn1A;
        acc[0][1] += a01 * ws1B + n1.x * wn1B;
        acc[1][0] += a11 * ws1A + n1.y * wn1A;
        acc[1][1] += a11 * ws1B + n1.y * wn1B;
    }

    if (!LAST) {
#pragma unroll
        for (int i = 0; i < 2; ++i) {
            int node = node0 + 2 * ty + i;
            if (node < NN) {
                float o0 = acc[i][0].x > 0.f ? acc[i][0].x : 0.f;
                float o1 = acc[i][0].y > 0.f ? acc[i][0].y : 0.f;
                float o2 = acc[i][1].x > 0.f ? acc[i][1].x : 0.f;
                float o3 = acc[i][1].y > 0.f ? acc[i][1].y : 0.f;
                uint2 p;
                p.x = bf16rne(o0) | (bf16rne(o1) << 16);
                p.y = bf16rne(o2) | (bf16rne(o3) << 16);
                outb[node * 16 + tx] = p;
            }
        }
    } else {
        // fused final GEMM: h2 tile -> NsT (reused, swizzled); Wfc reuses Wpk storage
        __syncthreads();
        float* Wf = (float*)Wpk;
#pragma unroll
        for (int i = 0; i < 2; ++i) {
            NsT[nswz(4 * tx + 0, 2 * ty + i)] = acc[i][0].x;
            NsT[nswz(4 * tx + 1, 2 * ty + i)] = acc[i][0].y;
            NsT[nswz(4 * tx + 2, 2 * ty + i)] = acc[i][1].x;
            NsT[nswz(4 * tx + 3, 2 * ty + i)] = acc[i][1].y;
        }
        for (int i = tid; i < F * F / 4; i += 512)
            ((float4*)Wf)[i] = ((const float4*)Wfc)[i];
        __syncthreads();

        f32x2 acc2[2][2];
        {
            f32x2 b01, b23;
            b01.x = bfc[4 * tx + 0]; b01.y = bfc[4 * tx + 1];
            b23.x = bfc[4 * tx + 2]; b23.y = bfc[4 * tx + 3];
            acc2[0][0] = b01; acc2[0][1] = b23;
            acc2[1][0] = b01; acc2[1][1] = b23;
        }
#pragma unroll 4
        for (int k = 0; k < 64; ++k) {
            float2 a2 = *(const float2*)&NsT[nswz(k, 2 * ty)];
            float4 w4 = *(const float4*)&Wf[k * 64 + 4 * tx];
            f32x2 wA, wB;
            wA.x = w4.x; wA.y = w4.y; wB.x = w4.z; wB.y = w4.w;
            acc2[0][0] += a2.x * wA; acc2[0][1] += a2.x * wB;
            acc2[1][0] += a2.y * wA; acc2[1][1] += a2.y * wB;
        }
#pragma unroll
        for (int i = 0; i < 2; ++i) {
            int node = node0 + 2 * ty + i;
            if (node < NN) {
                f32x4 o;
                o.x = acc2[i][0].x; o.y = acc2[i][0].y;
                o.z = acc2[i][1].x; o.w = acc2[i][1].y;
                __builtin_nontemporal_store(o, (f32x4*)&out[node * 64 + 4 * tx]);
            }
        }
    }
}

// ---------------- launch ----------------

extern "C" void kernel_launch(void* const* d_in, const int* in_sizes, int n_in,
                              void* d_out, int out_size, void* d_ws, size_t ws_size,
                              hipStream_t stream) {
    const float* embed = (const float*)d_in[0];
    const float* W1s = (const float*)d_in[1];
    const float* W1n = (const float*)d_in[2];
    const float* b1  = (const float*)d_in[3];
    const float* W2s = (const float*)d_in[4];
    const float* W2n = (const float*)d_in[5];
    const float* b2  = (const float*)d_in[6];
    const float* Wfc = (const float*)d_in[7];
    const float* bfc = (const float*)d_in[8];
    const int* ids = (const int*)d_in[9];
    const int* src = (const int*)d_in[10];
    const int* dst = (const int*)d_in[11];
    float* out = (float*)d_out;

    char* ws = (char*)d_ws;
    size_t off = 0;
    auto alloc = [&](size_t nb) {
        char* p = ws + off;
        off = (off + nb + 255) & ~(size_t)255;
        return p;
    };
    int*   cnt      = (int*)alloc(NN * sizeof(int));        // zeroed
    size_t zero_bytes = off;
    int*   offs     = (int*)alloc((NN + 1) * sizeof(int));
    int*   partials = (int*)alloc(SCAN_B * sizeof(int));
    unsigned short* pos = (unsigned short*)alloc(NE * sizeof(unsigned short));
    unsigned short* csr = (unsigned short*)alloc(NE * sizeof(unsigned short));
    uint2* xb       = (uint2*)alloc((size_t)NN * 16 * sizeof(uint2));  // bf16 x
    uint2* h1b      = (uint2*)alloc((size_t)NN * 16 * sizeof(uint2));  // bf16 h1

    hipMemsetAsync(d_ws, 0, zero_bytes, stream);

    const int TB = 256;
    const int EB = (NE + TB - 1) / TB;     // 3125
    k_count_gather<<<EB, TB, 0, stream>>>(dst, cnt, pos, embed, ids, xb);
    k_scan_a<<<SCAN_B, 256, 0, stream>>>(cnt, partials);
    k_scan_c2<<<SCAN_B, 256, 0, stream>>>(cnt, partials, offs);
    k_fill<<<EB, TB, 0, stream>>>(src, dst, offs, pos, csr);

    const int NB = (NN + 63) / 64;         // 782
    k_fused<false><<<NB, 512, 0, stream>>>((const uint4*)xb, offs, csr,
                                           W1s, W1n, b1, nullptr, nullptr,
                                           h1b, nullptr);
    k_fused<true><<<NB, 512, 0, stream>>>((const uint4*)h1b, offs, csr,
                                          W2s, W2n, b2, Wfc, bfc,
                                          nullptr, out);
}